// Round 6
// baseline (553.857 us; speedup 1.0000x reference)
//
#include <hip/hip_runtime.h>

// GraphSAGE 3-layer, N=50000, E=1.6M, D=128.
// R6: z stored quarter-major (4 x 3.2MB column slabs); aggregate swizzled so
//     blockIdx%4 = quarter -> each XCD's L2 holds one slab (gather = L2 BW).

constexpr int N_NODES = 50000;
constexpr int N_EDGES = 1600000;
constexpr int D = 128;
constexpr int SCAN_BLK = 1024;
constexpr int NCHUNK = (N_NODES + SCAN_BLK - 1) / SCAN_BLK;  // 49

typedef __bf16 bf16x8 __attribute__((ext_vector_type(8)));
typedef float f32x4 __attribute__((ext_vector_type(4)));
union U8 { bf16x8 v; __bf16 e[8]; };

// ---------------- zero counts -------------------------------------------
__global__ void zero1(int* __restrict__ a, int n) {
    int i = blockIdx.x * blockDim.x + threadIdx.x;
    if (i < n) a[i] = 0;
}

// ---------------- hist + per-edge position ------------------------------
__global__ void hist_pos(const int* __restrict__ dst, int* __restrict__ counts,
                         int* __restrict__ pos, int n) {
    int e = blockIdx.x * blockDim.x + threadIdx.x;
    if (e < n) pos[e] = atomicAdd(&counts[dst[e]], 1);
}

// ---------------- scan phase 1 ------------------------------------------
__global__ __launch_bounds__(SCAN_BLK) void scan_p1(const int* __restrict__ counts,
                                                    int* __restrict__ row_ptr,
                                                    float* __restrict__ inv_deg,
                                                    int* __restrict__ blocksums) {
    __shared__ int wsum[16];
    __shared__ int wpre[16];
    const int t = threadIdx.x;
    const int i = blockIdx.x * SCAN_BLK + t;
    const int lane = t & 63, w = t >> 6;
    int v = (i < N_NODES) ? counts[i] : 0;
    int x = v;
    #pragma unroll
    for (int off = 1; off < 64; off <<= 1) {
        int tt = __shfl_up(x, off, 64);
        if (lane >= off) x += tt;
    }
    if (lane == 63) wsum[w] = x;
    __syncthreads();
    if (t < 16) {
        int s = wsum[t];
        int y = s;
        #pragma unroll
        for (int off = 1; off < 16; off <<= 1) {
            int tt = __shfl_up(y, off, 64);
            if (t >= off) y += tt;
        }
        wpre[t] = y - s;
    }
    __syncthreads();
    if (i < N_NODES) {
        row_ptr[i] = wpre[w] + (x - v);
        inv_deg[i] = 1.0f / fmaxf((float)v, 1.0f);
    }
    if (t == SCAN_BLK - 1) blocksums[blockIdx.x] = wpre[15] + wsum[15];
}

// ---------------- scan phase 2 ------------------------------------------
__global__ void scan_p2(const int* __restrict__ blocksums, int* __restrict__ blockoffs) {
    const int t = threadIdx.x;
    int v = (t < NCHUNK) ? blocksums[t] : 0;
    int x = v;
    #pragma unroll
    for (int off = 1; off < 64; off <<= 1) {
        int tt = __shfl_up(x, off, 64);
        if (t >= off) x += tt;
    }
    if (t < NCHUNK) blockoffs[t] = x - v;
}

// ---------------- scan phase 3 ------------------------------------------
__global__ __launch_bounds__(SCAN_BLK) void scan_p3(int* __restrict__ row_ptr,
                                                    const int* __restrict__ blockoffs) {
    const int i = blockIdx.x * SCAN_BLK + threadIdx.x;
    if (i < N_NODES) row_ptr[i] += blockoffs[blockIdx.x];
    if (i == 0) row_ptr[N_NODES] = N_EDGES;
}

// ---------------- atomic-free edge scatter -------------------------------
__global__ void scatter_edges(const int* __restrict__ src, const int* __restrict__ dst,
                              const int* __restrict__ pos, const int* __restrict__ row_ptr,
                              int* __restrict__ esrc, int n) {
    int e = blockIdx.x * blockDim.x + threadIdx.x;
    if (e < n) esrc[row_ptr[dst[e]] + pos[e]] = src[e];
}

// ---------------- pack W into MFMA B-fragment order, hi+lo ---------------
__global__ void pack_w(const float* __restrict__ w0, const float* __restrict__ w1,
                       const float* __restrict__ w2, const float* __restrict__ w3,
                       const float* __restrict__ w4, const float* __restrict__ w5,
                       __bf16* __restrict__ outbase) {
    const float* ws[6] = {w0, w1, w2, w3, w4, w5};
    const float* W = ws[blockIdx.y];
    __bf16* o = outbase + (size_t)blockIdx.y * 32768;
    int idx = blockIdx.x * 256 + threadIdx.x;   // 0..16383
    int t = idx & 7;
    int lane = (idx >> 3) & 63;
    int ks = (idx >> 9) & 3;
    int jt = idx >> 11;
    int j = jt * 16 + (lane & 15);
    int k = ks * 32 + (lane >> 4) * 8 + t;
    float w = W[j * D + k];
    __bf16 hi = (__bf16)w;
    o[idx] = hi;
    o[16384 + idx] = (__bf16)(w - (float)hi);
}

// ---------------- dual GEMM: y = h@Ws^T + b (fp32), z = h@Wn^T (bf16) ----
// z written quarter-major: z[(q*N + n)*32 + (j&31)], q = j>>5.
__global__ __launch_bounds__(256) void dual_gemm(
        const float* __restrict__ h, const __bf16* __restrict__ Bs,
        const __bf16* __restrict__ Bn, const float* __restrict__ bias,
        float* __restrict__ y_self, __bf16* __restrict__ z) {
    const int wave = threadIdx.x >> 6;
    const int lane = threadIdx.x & 63;
    const int tile = blockIdx.x * 4 + wave;
    if (tile >= N_NODES / 16) return;
    const int n0 = tile * 16;
    const int row = n0 + (lane & 15);
    const int koff = (lane >> 4) * 8;

    U8 ahi[4], alo[4];
    #pragma unroll
    for (int ks = 0; ks < 4; ++ks) {
        const float* p = h + (size_t)row * D + ks * 32 + koff;
        float f[8];
        *(f32x4*)&f[0] = *(const f32x4*)p;
        *(f32x4*)&f[4] = *(const f32x4*)(p + 4);
        #pragma unroll
        for (int t = 0; t < 8; ++t) {
            __bf16 hi = (__bf16)f[t];
            ahi[ks].e[t] = hi;
            alo[ks].e[t] = (__bf16)(f[t] - (float)hi);
        }
    }

    const int jcol = lane & 15;
    const int r0 = (lane >> 4) * 4;

    #pragma unroll 2
    for (int jt = 0; jt < 8; ++jt) {
        f32x4 accS = {0.f, 0.f, 0.f, 0.f};
        f32x4 accN = {0.f, 0.f, 0.f, 0.f};
        #pragma unroll
        for (int ks = 0; ks < 4; ++ks) {
            const size_t off = (((size_t)jt * 4 + ks) * 64 + lane) * 8;
            bf16x8 wsh = *(const bf16x8*)(Bs + off);
            bf16x8 wsl = *(const bf16x8*)(Bs + 16384 + off);
            bf16x8 wnh = *(const bf16x8*)(Bn + off);
            bf16x8 wnl = *(const bf16x8*)(Bn + 16384 + off);
            accS = __builtin_amdgcn_mfma_f32_16x16x32_bf16(ahi[ks].v, wsh, accS, 0, 0, 0);
            accS = __builtin_amdgcn_mfma_f32_16x16x32_bf16(alo[ks].v, wsh, accS, 0, 0, 0);
            accS = __builtin_amdgcn_mfma_f32_16x16x32_bf16(ahi[ks].v, wsl, accS, 0, 0, 0);
            accN = __builtin_amdgcn_mfma_f32_16x16x32_bf16(ahi[ks].v, wnh, accN, 0, 0, 0);
            accN = __builtin_amdgcn_mfma_f32_16x16x32_bf16(alo[ks].v, wnh, accN, 0, 0, 0);
            accN = __builtin_amdgcn_mfma_f32_16x16x32_bf16(ahi[ks].v, wnl, accN, 0, 0, 0);
        }
        const int j = jt * 16 + jcol;
        const float bj = bias[j];
        const size_t zslab = (size_t)(j >> 5) * N_NODES;
        #pragma unroll
        for (int r = 0; r < 4; ++r) {
            const size_t n = n0 + r0 + r;
            y_self[n * D + j] = accS[r] + bj;
            z[(zslab + n) * 32 + (j & 31)] = (__bf16)accN[r];
        }
    }
}

// ---------------- aggregate z (quarter-slab) + add y_self (+relu) --------
// blockIdx%4 = quarter -> XCD L2 affinity. One wave per (node, quarter):
// 16 edge slots x 4 lanes x 16B (the 64B quarter-row).
__global__ __launch_bounds__(256) void agg_add(
        const __bf16* __restrict__ zq, const int* __restrict__ esrc,
        const int* __restrict__ row_ptr, const float* __restrict__ inv_deg,
        const float* __restrict__ y_self, float* __restrict__ out, int do_relu) {
    const int q = blockIdx.x & 3;
    const int grp = blockIdx.x >> 2;
    const int n = grp * 4 + (threadIdx.x >> 6);
    const int lane = threadIdx.x & 63;
    const int slot = lane >> 2;   // 0..15
    const int cl = lane & 3;      // 0..3
    const int r0 = row_ptr[n], r1 = row_ptr[n + 1];
    const __bf16* zbase = zq + (size_t)q * N_NODES * 32 + cl * 8;

    float acc[8] = {0.f, 0.f, 0.f, 0.f, 0.f, 0.f, 0.f, 0.f};
    int e = r0 + slot;
    for (; e + 16 < r1; e += 32) {
        int i0 = __builtin_nontemporal_load(esrc + e);
        int i1 = __builtin_nontemporal_load(esrc + e + 16);
        U8 v0, v1;
        v0.v = *(const bf16x8*)(zbase + (size_t)i0 * 32);
        v1.v = *(const bf16x8*)(zbase + (size_t)i1 * 32);
        #pragma unroll
        for (int t = 0; t < 8; ++t) acc[t] += (float)v0.e[t] + (float)v1.e[t];
    }
    for (; e < r1; e += 16) {
        int i0 = __builtin_nontemporal_load(esrc + e);
        U8 v0;
        v0.v = *(const bf16x8*)(zbase + (size_t)i0 * 32);
        #pragma unroll
        for (int t = 0; t < 8; ++t) acc[t] += (float)v0.e[t];
    }
    #pragma unroll
    for (int t = 0; t < 8; ++t) acc[t] += __shfl_down(acc[t], 32, 64);
    #pragma unroll
    for (int t = 0; t < 8; ++t) acc[t] += __shfl_down(acc[t], 16, 64);
    #pragma unroll
    for (int t = 0; t < 8; ++t) acc[t] += __shfl_down(acc[t], 8, 64);
    #pragma unroll
    for (int t = 0; t < 8; ++t) acc[t] += __shfl_down(acc[t], 4, 64);

    if (lane < 4) {
        const float idg = inv_deg[n];
        const float* yp = y_self + (size_t)n * D + q * 32 + cl * 8;
        f32x4 y0 = *(const f32x4*)yp;
        f32x4 y1 = *(const f32x4*)(yp + 4);
        float o[8];
        #pragma unroll
        for (int t = 0; t < 4; ++t) o[t] = y0[t] + acc[t] * idg;
        #pragma unroll
        for (int t = 0; t < 4; ++t) o[4 + t] = y1[t] + acc[4 + t] * idg;
        if (do_relu) {
            #pragma unroll
            for (int t = 0; t < 8; ++t) o[t] = fmaxf(o[t], 0.f);
        }
        float* op = out + (size_t)n * D + q * 32 + cl * 8;
        *(f32x4*)op = *(f32x4*)&o[0];
        *(f32x4*)(op + 4) = *(f32x4*)&o[4];
    }
}

extern "C" void kernel_launch(void* const* d_in, const int* in_sizes, int n_in,
                              void* d_out, int out_size, void* d_ws, size_t ws_size,
                              hipStream_t stream) {
    const float* x   = (const float*)d_in[0];
    const int* src   = (const int*)d_in[1];
    const int* dst   = (const int*)d_in[2];
    const float* Wn1 = (const float*)d_in[3];
    const float* Ws1 = (const float*)d_in[4];
    const float* b1  = (const float*)d_in[5];
    const float* Wn2 = (const float*)d_in[6];
    const float* Ws2 = (const float*)d_in[7];
    const float* b2  = (const float*)d_in[8];
    const float* Wn3 = (const float*)d_in[9];
    const float* Ws3 = (const float*)d_in[10];
    const float* b3  = (const float*)d_in[11];
    float* out = (float*)d_out;

    char* w = (char*)d_ws;
    float* inv_deg  = (float*)w;                w += 50176 * 4;
    int* counts     = (int*)w;                  w += 50176 * 4;
    int* row_ptr    = (int*)w;                  w += 50432 * 4;
    int* blocksums  = (int*)w;                  w += 64 * 4;
    int* blockoffs  = (int*)w;                  w += 64 * 4;
    int* esrc       = (int*)w;                  w += (size_t)N_EDGES * 4;
    __bf16* Bpk     = (__bf16*)w;               w += 6 * 32768 * 2;
    __bf16* zbuf    = (__bf16*)w;               w += (size_t)N_NODES * D * 2;  // 4 slabs
    float* bufA     = (float*)w;                // N*D floats

    int* pos = (int*)zbuf;   // pos[] dead once zbuf is first written

    const __bf16* PWs1 = Bpk + 0 * 32768, *PWn1 = Bpk + 1 * 32768;
    const __bf16* PWs2 = Bpk + 2 * 32768, *PWn2 = Bpk + 3 * 32768;
    const __bf16* PWs3 = Bpk + 4 * 32768, *PWn3 = Bpk + 5 * 32768;

    // ---- CSR build ----
    zero1<<<(50176 + 255) / 256, 256, 0, stream>>>(counts, 50176);
    hist_pos<<<(N_EDGES + 511) / 512, 512, 0, stream>>>(dst, counts, pos, N_EDGES);
    scan_p1<<<NCHUNK, SCAN_BLK, 0, stream>>>(counts, row_ptr, inv_deg, blocksums);
    scan_p2<<<1, 64, 0, stream>>>(blocksums, blockoffs);
    scan_p3<<<NCHUNK, SCAN_BLK, 0, stream>>>(row_ptr, blockoffs);
    scatter_edges<<<(N_EDGES + 511) / 512, 512, 0, stream>>>(src, dst, pos, row_ptr,
                                                             esrc, N_EDGES);
    pack_w<<<dim3(64, 6), 256, 0, stream>>>(Ws1, Wn1, Ws2, Wn2, Ws3, Wn3, Bpk);

    const int ggrid = (N_NODES / 16 + 3) / 4;   // 782
    const int agrid = (N_NODES / 4) * 4;        // 50000 blocks: grp*4 + quarter

    // layer 1: h=x -> bufA (relu)
    dual_gemm<<<ggrid, 256, 0, stream>>>(x, PWs1, PWn1, b1, bufA, zbuf);
    agg_add<<<agrid, 256, 0, stream>>>(zbuf, esrc, row_ptr, inv_deg, bufA, bufA, 1);

    // layer 2: h=bufA -> d_out (relu)
    dual_gemm<<<ggrid, 256, 0, stream>>>(bufA, PWs2, PWn2, b2, out, zbuf);
    agg_add<<<agrid, 256, 0, stream>>>(zbuf, esrc, row_ptr, inv_deg, out, out, 1);

    // layer 3: h=d_out -> d_out (no relu), y_self staged in bufA
    dual_gemm<<<ggrid, 256, 0, stream>>>(out, PWs3, PWn3, b3, bufA, zbuf);
    agg_add<<<agrid, 256, 0, stream>>>(zbuf, esrc, row_ptr, inv_deg, bufA, out, 0);
}

// Round 7
// 495.913 us; speedup vs baseline: 1.1168x; 1.1168x over previous
//
#include <hip/hip_runtime.h>

// GraphSAGE 3-layer, N=50000, E=1.6M, D=128.
// R7: quarter-slab L2 locality (R6) + 4-nodes-per-wave amortization (R5):
//     block = 16 nodes x 1 quarter, lane = (node:2)(slot:2)(chunk:2).

constexpr int N_NODES = 50000;
constexpr int N_EDGES = 1600000;
constexpr int D = 128;
constexpr int SCAN_BLK = 1024;
constexpr int NCHUNK = (N_NODES + SCAN_BLK - 1) / SCAN_BLK;  // 49

typedef __bf16 bf16x8 __attribute__((ext_vector_type(8)));
typedef float f32x4 __attribute__((ext_vector_type(4)));
union U8 { bf16x8 v; __bf16 e[8]; };

// ---------------- zero counts -------------------------------------------
__global__ void zero1(int* __restrict__ a, int n) {
    int i = blockIdx.x * blockDim.x + threadIdx.x;
    if (i < n) a[i] = 0;
}

// ---------------- hist + per-edge position ------------------------------
__global__ void hist_pos(const int* __restrict__ dst, int* __restrict__ counts,
                         int* __restrict__ pos, int n) {
    int e = blockIdx.x * blockDim.x + threadIdx.x;
    if (e < n) pos[e] = atomicAdd(&counts[dst[e]], 1);
}

// ---------------- scan phase 1 ------------------------------------------
__global__ __launch_bounds__(SCAN_BLK) void scan_p1(const int* __restrict__ counts,
                                                    int* __restrict__ row_ptr,
                                                    float* __restrict__ inv_deg,
                                                    int* __restrict__ blocksums) {
    __shared__ int wsum[16];
    __shared__ int wpre[16];
    const int t = threadIdx.x;
    const int i = blockIdx.x * SCAN_BLK + t;
    const int lane = t & 63, w = t >> 6;
    int v = (i < N_NODES) ? counts[i] : 0;
    int x = v;
    #pragma unroll
    for (int off = 1; off < 64; off <<= 1) {
        int tt = __shfl_up(x, off, 64);
        if (lane >= off) x += tt;
    }
    if (lane == 63) wsum[w] = x;
    __syncthreads();
    if (t < 16) {
        int s = wsum[t];
        int y = s;
        #pragma unroll
        for (int off = 1; off < 16; off <<= 1) {
            int tt = __shfl_up(y, off, 64);
            if (t >= off) y += tt;
        }
        wpre[t] = y - s;
    }
    __syncthreads();
    if (i < N_NODES) {
        row_ptr[i] = wpre[w] + (x - v);
        inv_deg[i] = 1.0f / fmaxf((float)v, 1.0f);
    }
    if (t == SCAN_BLK - 1) blocksums[blockIdx.x] = wpre[15] + wsum[15];
}

// ---------------- scan phase 2 ------------------------------------------
__global__ void scan_p2(const int* __restrict__ blocksums, int* __restrict__ blockoffs) {
    const int t = threadIdx.x;
    int v = (t < NCHUNK) ? blocksums[t] : 0;
    int x = v;
    #pragma unroll
    for (int off = 1; off < 64; off <<= 1) {
        int tt = __shfl_up(x, off, 64);
        if (t >= off) x += tt;
    }
    if (t < NCHUNK) blockoffs[t] = x - v;
}

// ---------------- scan phase 3 ------------------------------------------
__global__ __launch_bounds__(SCAN_BLK) void scan_p3(int* __restrict__ row_ptr,
                                                    const int* __restrict__ blockoffs) {
    const int i = blockIdx.x * SCAN_BLK + threadIdx.x;
    if (i < N_NODES) row_ptr[i] += blockoffs[blockIdx.x];
    if (i == 0) row_ptr[N_NODES] = N_EDGES;
}

// ---------------- atomic-free edge scatter -------------------------------
__global__ void scatter_edges(const int* __restrict__ src, const int* __restrict__ dst,
                              const int* __restrict__ pos, const int* __restrict__ row_ptr,
                              int* __restrict__ esrc, int n) {
    int e = blockIdx.x * blockDim.x + threadIdx.x;
    if (e < n) esrc[row_ptr[dst[e]] + pos[e]] = src[e];
}

// ---------------- pack W into MFMA B-fragment order, hi+lo ---------------
__global__ void pack_w(const float* __restrict__ w0, const float* __restrict__ w1,
                       const float* __restrict__ w2, const float* __restrict__ w3,
                       const float* __restrict__ w4, const float* __restrict__ w5,
                       __bf16* __restrict__ outbase) {
    const float* ws[6] = {w0, w1, w2, w3, w4, w5};
    const float* W = ws[blockIdx.y];
    __bf16* o = outbase + (size_t)blockIdx.y * 32768;
    int idx = blockIdx.x * 256 + threadIdx.x;   // 0..16383
    int t = idx & 7;
    int lane = (idx >> 3) & 63;
    int ks = (idx >> 9) & 3;
    int jt = idx >> 11;
    int j = jt * 16 + (lane & 15);
    int k = ks * 32 + (lane >> 4) * 8 + t;
    float w = W[j * D + k];
    __bf16 hi = (__bf16)w;
    o[idx] = hi;
    o[16384 + idx] = (__bf16)(w - (float)hi);
}

// ---------------- dual GEMM: y = h@Ws^T + b (fp32), z = h@Wn^T (bf16) ----
// z written quarter-major: z[(q*N + n)*32 + (j&31)], q = j>>5.
__global__ __launch_bounds__(256) void dual_gemm(
        const float* __restrict__ h, const __bf16* __restrict__ Bs,
        const __bf16* __restrict__ Bn, const float* __restrict__ bias,
        float* __restrict__ y_self, __bf16* __restrict__ z) {
    const int wave = threadIdx.x >> 6;
    const int lane = threadIdx.x & 63;
    const int tile = blockIdx.x * 4 + wave;
    if (tile >= N_NODES / 16) return;
    const int n0 = tile * 16;
    const int row = n0 + (lane & 15);
    const int koff = (lane >> 4) * 8;

    U8 ahi[4], alo[4];
    #pragma unroll
    for (int ks = 0; ks < 4; ++ks) {
        const float* p = h + (size_t)row * D + ks * 32 + koff;
        float f[8];
        *(f32x4*)&f[0] = *(const f32x4*)p;
        *(f32x4*)&f[4] = *(const f32x4*)(p + 4);
        #pragma unroll
        for (int t = 0; t < 8; ++t) {
            __bf16 hi = (__bf16)f[t];
            ahi[ks].e[t] = hi;
            alo[ks].e[t] = (__bf16)(f[t] - (float)hi);
        }
    }

    const int jcol = lane & 15;
    const int r0 = (lane >> 4) * 4;

    #pragma unroll 2
    for (int jt = 0; jt < 8; ++jt) {
        f32x4 accS = {0.f, 0.f, 0.f, 0.f};
        f32x4 accN = {0.f, 0.f, 0.f, 0.f};
        #pragma unroll
        for (int ks = 0; ks < 4; ++ks) {
            const size_t off = (((size_t)jt * 4 + ks) * 64 + lane) * 8;
            bf16x8 wsh = *(const bf16x8*)(Bs + off);
            bf16x8 wsl = *(const bf16x8*)(Bs + 16384 + off);
            bf16x8 wnh = *(const bf16x8*)(Bn + off);
            bf16x8 wnl = *(const bf16x8*)(Bn + 16384 + off);
            accS = __builtin_amdgcn_mfma_f32_16x16x32_bf16(ahi[ks].v, wsh, accS, 0, 0, 0);
            accS = __builtin_amdgcn_mfma_f32_16x16x32_bf16(alo[ks].v, wsh, accS, 0, 0, 0);
            accS = __builtin_amdgcn_mfma_f32_16x16x32_bf16(ahi[ks].v, wsl, accS, 0, 0, 0);
            accN = __builtin_amdgcn_mfma_f32_16x16x32_bf16(ahi[ks].v, wnh, accN, 0, 0, 0);
            accN = __builtin_amdgcn_mfma_f32_16x16x32_bf16(alo[ks].v, wnh, accN, 0, 0, 0);
            accN = __builtin_amdgcn_mfma_f32_16x16x32_bf16(ahi[ks].v, wnl, accN, 0, 0, 0);
        }
        const int j = jt * 16 + jcol;
        const float bj = bias[j];
        const size_t zslab = (size_t)(j >> 5) * N_NODES;
        #pragma unroll
        for (int r = 0; r < 4; ++r) {
            const size_t n = n0 + r0 + r;
            y_self[n * D + j] = accS[r] + bj;
            z[(zslab + n) * 32 + (j & 31)] = (__bf16)accN[r];
        }
    }
}

// ---------------- aggregate z (quarter-slab) + add y_self (+relu) --------
// blockIdx%4 = q -> XCD L2 affinity. Block = 16 nodes x quarter q.
// Wave handles 4 nodes; lane = (g:2)(sl:2)(cl:2) -> 16 edges in flight.
__global__ __launch_bounds__(256) void agg_add(
        const __bf16* __restrict__ zq, const int* __restrict__ esrc,
        const int* __restrict__ row_ptr, const float* __restrict__ inv_deg,
        const float* __restrict__ y_self, float* __restrict__ out, int do_relu) {
    const int q = blockIdx.x & 3;
    const int grp = blockIdx.x >> 2;                  // 0..3124
    const int wave = threadIdx.x >> 6;
    const int lane = threadIdx.x & 63;
    const int g  = lane >> 4;                          // node sub-index 0..3
    const int sl = (lane >> 2) & 3;                    // edge slot 0..3
    const int cl = lane & 3;                           // 16B chunk 0..3
    const int n = grp * 16 + wave * 4 + g;
    const int r0 = row_ptr[n], r1 = row_ptr[n + 1];
    const __bf16* zbase = zq + (size_t)q * N_NODES * 32 + cl * 8;

    float acc[8] = {0.f, 0.f, 0.f, 0.f, 0.f, 0.f, 0.f, 0.f};
    int e = r0 + sl;
    for (; e + 12 < r1; e += 16) {
        int i0 = __builtin_nontemporal_load(esrc + e);
        int i1 = __builtin_nontemporal_load(esrc + e + 4);
        int i2 = __builtin_nontemporal_load(esrc + e + 8);
        int i3 = __builtin_nontemporal_load(esrc + e + 12);
        U8 v0, v1, v2, v3;
        v0.v = *(const bf16x8*)(zbase + (size_t)i0 * 32);
        v1.v = *(const bf16x8*)(zbase + (size_t)i1 * 32);
        v2.v = *(const bf16x8*)(zbase + (size_t)i2 * 32);
        v3.v = *(const bf16x8*)(zbase + (size_t)i3 * 32);
        #pragma unroll
        for (int t = 0; t < 8; ++t)
            acc[t] += ((float)v0.e[t] + (float)v1.e[t]) + ((float)v2.e[t] + (float)v3.e[t]);
    }
    for (; e < r1; e += 4) {
        int i0 = __builtin_nontemporal_load(esrc + e);
        U8 v0;
        v0.v = *(const bf16x8*)(zbase + (size_t)i0 * 32);
        #pragma unroll
        for (int t = 0; t < 8; ++t) acc[t] += (float)v0.e[t];
    }
    // fold 4 slots -> slot 0 (within each 16-lane node group)
    #pragma unroll
    for (int t = 0; t < 8; ++t) acc[t] += __shfl_down(acc[t], 8, 64);
    #pragma unroll
    for (int t = 0; t < 8; ++t) acc[t] += __shfl_down(acc[t], 4, 64);

    if (sl == 0) {
        const float idg = inv_deg[n];
        const float* yp = y_self + (size_t)n * D + q * 32 + cl * 8;
        f32x4 y0 = *(const f32x4*)yp;
        f32x4 y1 = *(const f32x4*)(yp + 4);
        float o[8];
        #pragma unroll
        for (int t = 0; t < 4; ++t) o[t] = y0[t] + acc[t] * idg;
        #pragma unroll
        for (int t = 0; t < 4; ++t) o[4 + t] = y1[t] + acc[4 + t] * idg;
        if (do_relu) {
            #pragma unroll
            for (int t = 0; t < 8; ++t) o[t] = fmaxf(o[t], 0.f);
        }
        float* op = out + (size_t)n * D + q * 32 + cl * 8;
        *(f32x4*)op = *(f32x4*)&o[0];
        *(f32x4*)(op + 4) = *(f32x4*)&o[4];
    }
}

extern "C" void kernel_launch(void* const* d_in, const int* in_sizes, int n_in,
                              void* d_out, int out_size, void* d_ws, size_t ws_size,
                              hipStream_t stream) {
    const float* x   = (const float*)d_in[0];
    const int* src   = (const int*)d_in[1];
    const int* dst   = (const int*)d_in[2];
    const float* Wn1 = (const float*)d_in[3];
    const float* Ws1 = (const float*)d_in[4];
    const float* b1  = (const float*)d_in[5];
    const float* Wn2 = (const float*)d_in[6];
    const float* Ws2 = (const float*)d_in[7];
    const float* b2  = (const float*)d_in[8];
    const float* Wn3 = (const float*)d_in[9];
    const float* Ws3 = (const float*)d_in[10];
    const float* b3  = (const float*)d_in[11];
    float* out = (float*)d_out;

    char* w = (char*)d_ws;
    float* inv_deg  = (float*)w;                w += 50176 * 4;
    int* counts     = (int*)w;                  w += 50176 * 4;
    int* row_ptr    = (int*)w;                  w += 50432 * 4;
    int* blocksums  = (int*)w;                  w += 64 * 4;
    int* blockoffs  = (int*)w;                  w += 64 * 4;
    int* esrc       = (int*)w;                  w += (size_t)N_EDGES * 4;
    __bf16* Bpk     = (__bf16*)w;               w += 6 * 32768 * 2;
    __bf16* zbuf    = (__bf16*)w;               w += (size_t)N_NODES * D * 2;  // 4 slabs
    float* bufA     = (float*)w;                // N*D floats

    int* pos = (int*)zbuf;   // pos[] dead once zbuf is first written

    const __bf16* PWs1 = Bpk + 0 * 32768, *PWn1 = Bpk + 1 * 32768;
    const __bf16* PWs2 = Bpk + 2 * 32768, *PWn2 = Bpk + 3 * 32768;
    const __bf16* PWs3 = Bpk + 4 * 32768, *PWn3 = Bpk + 5 * 32768;

    // ---- CSR build ----
    zero1<<<(50176 + 255) / 256, 256, 0, stream>>>(counts, 50176);
    hist_pos<<<(N_EDGES + 511) / 512, 512, 0, stream>>>(dst, counts, pos, N_EDGES);
    scan_p1<<<NCHUNK, SCAN_BLK, 0, stream>>>(counts, row_ptr, inv_deg, blocksums);
    scan_p2<<<1, 64, 0, stream>>>(blocksums, blockoffs);
    scan_p3<<<NCHUNK, SCAN_BLK, 0, stream>>>(row_ptr, blockoffs);
    scatter_edges<<<(N_EDGES + 511) / 512, 512, 0, stream>>>(src, dst, pos, row_ptr,
                                                             esrc, N_EDGES);
    pack_w<<<dim3(64, 6), 256, 0, stream>>>(Ws1, Wn1, Ws2, Wn2, Ws3, Wn3, Bpk);

    const int ggrid = (N_NODES / 16 + 3) / 4;     // 782
    const int agrid = (N_NODES / 16) * 4;         // 12500: grp*4 + quarter

    // layer 1: h=x -> bufA (relu)
    dual_gemm<<<ggrid, 256, 0, stream>>>(x, PWs1, PWn1, b1, bufA, zbuf);
    agg_add<<<agrid, 256, 0, stream>>>(zbuf, esrc, row_ptr, inv_deg, bufA, bufA, 1);

    // layer 2: h=bufA -> d_out (relu)
    dual_gemm<<<ggrid, 256, 0, stream>>>(bufA, PWs2, PWn2, b2, out, zbuf);
    agg_add<<<agrid, 256, 0, stream>>>(zbuf, esrc, row_ptr, inv_deg, out, out, 1);

    // layer 3: h=d_out -> d_out (no relu), y_self staged in bufA
    dual_gemm<<<ggrid, 256, 0, stream>>>(out, PWs3, PWn3, b3, bufA, zbuf);
    agg_add<<<agrid, 256, 0, stream>>>(zbuf, esrc, row_ptr, inv_deg, bufA, out, 0);
}

// Round 9
// 475.360 us; speedup vs baseline: 1.1651x; 1.0432x over previous
//
#include <hip/hip_runtime.h>

// GraphSAGE 3-layer, N=50000, E=1.6M, D=128.
// R8b: slab-local agg + sentinel-padded CSR (no tail chains) +
//      y_self prefetch + 8-shadow histogram. Fix: ext_vector int4 for
//      __builtin_nontemporal_load.

constexpr int N_NODES = 50000;
constexpr int N_EDGES = 1600000;
constexpr int D = 128;
constexpr int SCAN_BLK = 1024;
constexpr int NCHUNK = (N_NODES + SCAN_BLK - 1) / SCAN_BLK;  // 49
constexpr int NSH = 50048;            // shadow stride (ints)
constexpr int ESRC_CAP = 2100000;     // padded-edge capacity (mult of 4)
constexpr int SENT = 50000;           // sentinel node id (zero z-row)
constexpr int ZROWS = 50001;          // slab rows incl sentinel

typedef __bf16 bf16x8 __attribute__((ext_vector_type(8)));
typedef float f32x4 __attribute__((ext_vector_type(4)));
typedef int i32x4 __attribute__((ext_vector_type(4)));
union U8 { bf16x8 v; __bf16 e[8]; };

// ---------------- zero shadow histograms --------------------------------
__global__ void zero_sh(i32x4* __restrict__ p, int n4) {
    int i = blockIdx.x * blockDim.x + threadIdx.x;
    if (i < n4) p[i] = (i32x4){0, 0, 0, 0};
}

// ---------------- fill esrc with sentinel --------------------------------
__global__ void fill_esrc(i32x4* __restrict__ p, int n4) {
    int i = blockIdx.x * blockDim.x + threadIdx.x;
    if (i < n4) p[i] = (i32x4){SENT, SENT, SENT, SENT};
}

// ---------------- zero the 4 sentinel z-rows -----------------------------
__global__ void zero_zrow(__bf16* __restrict__ z) {
    int t = threadIdx.x;            // 128 threads
    int q = t >> 5, c = t & 31;
    z[((size_t)q * ZROWS + SENT) * 32 + c] = (__bf16)0.f;
}

// ---------------- 8-shadow histogram + per-edge local pos ----------------
__global__ __launch_bounds__(512) void hist8(const int* __restrict__ dst,
                                             int* __restrict__ counts_sh,
                                             int* __restrict__ pos_local, int n) {
    int e = blockIdx.x * 512 + threadIdx.x;
    if (e < n) {
        int s = blockIdx.x & 7;
        pos_local[e] = atomicAdd(&counts_sh[s * NSH + dst[e]], 1);
    }
}

// ---------------- per-node shadow prefix + deg + padded count ------------
__global__ void shadow_scan(int* __restrict__ counts_sh, int* __restrict__ counts,
                            float* __restrict__ inv_deg) {
    int d = blockIdx.x * 256 + threadIdx.x;
    if (d >= N_NODES) return;
    int run = 0;
    #pragma unroll
    for (int s = 0; s < 8; ++s) {
        int c = counts_sh[s * NSH + d];
        counts_sh[s * NSH + d] = run;   // exclusive prefix in place
        run += c;
    }
    counts[d] = (run + 15) & ~15;       // padded count (mult of 16)
    inv_deg[d] = 1.0f / fmaxf((float)run, 1.0f);
}

// ---------------- scan phase 1 (padded counts -> local scan) -------------
__global__ __launch_bounds__(SCAN_BLK) void scan_p1(const int* __restrict__ counts,
                                                    int* __restrict__ row_ptr,
                                                    int* __restrict__ blocksums) {
    __shared__ int wsum[16];
    __shared__ int wpre[16];
    const int t = threadIdx.x;
    const int i = blockIdx.x * SCAN_BLK + t;
    const int lane = t & 63, w = t >> 6;
    int v = (i < N_NODES) ? counts[i] : 0;
    int x = v;
    #pragma unroll
    for (int off = 1; off < 64; off <<= 1) {
        int tt = __shfl_up(x, off, 64);
        if (lane >= off) x += tt;
    }
    if (lane == 63) wsum[w] = x;
    __syncthreads();
    if (t < 16) {
        int s = wsum[t];
        int y = s;
        #pragma unroll
        for (int off = 1; off < 16; off <<= 1) {
            int tt = __shfl_up(y, off, 64);
            if (t >= off) y += tt;
        }
        wpre[t] = y - s;
    }
    __syncthreads();
    if (i < N_NODES) row_ptr[i] = wpre[w] + (x - v);
    if (t == SCAN_BLK - 1) blocksums[blockIdx.x] = wpre[15] + wsum[15];
}

// ---------------- scan phase 2 ------------------------------------------
__global__ void scan_p2(const int* __restrict__ blocksums, int* __restrict__ blockoffs) {
    const int t = threadIdx.x;
    int v = (t < NCHUNK) ? blocksums[t] : 0;
    int x = v;
    #pragma unroll
    for (int off = 1; off < 64; off <<= 1) {
        int tt = __shfl_up(x, off, 64);
        if (t >= off) x += tt;
    }
    if (t < NCHUNK) blockoffs[t] = x - v;
}

// ---------------- scan phase 3 (+ total) ---------------------------------
__global__ __launch_bounds__(SCAN_BLK) void scan_p3(int* __restrict__ row_ptr,
                                                    const int* __restrict__ blockoffs,
                                                    const int* __restrict__ blocksums) {
    const int i = blockIdx.x * SCAN_BLK + threadIdx.x;
    if (i < N_NODES) row_ptr[i] += blockoffs[blockIdx.x];
    if (i == 0) row_ptr[N_NODES] = blockoffs[NCHUNK - 1] + blocksums[NCHUNK - 1];
}

// ---------------- scatter edges (atomic-free) ----------------------------
__global__ __launch_bounds__(512) void scatter8(const int* __restrict__ src,
                                                const int* __restrict__ dst,
                                                const int* __restrict__ pos_local,
                                                const int* __restrict__ counts_sh,
                                                const int* __restrict__ row_ptr,
                                                int* __restrict__ esrc, int n) {
    int e = blockIdx.x * 512 + threadIdx.x;
    if (e < n) {
        int d = dst[e];
        int s = blockIdx.x & 7;
        esrc[row_ptr[d] + counts_sh[s * NSH + d] + pos_local[e]] = src[e];
    }
}

// ---------------- pack W into MFMA B-fragment order, hi+lo ---------------
__global__ void pack_w(const float* __restrict__ w0, const float* __restrict__ w1,
                       const float* __restrict__ w2, const float* __restrict__ w3,
                       const float* __restrict__ w4, const float* __restrict__ w5,
                       __bf16* __restrict__ outbase) {
    const float* ws[6] = {w0, w1, w2, w3, w4, w5};
    const float* W = ws[blockIdx.y];
    __bf16* o = outbase + (size_t)blockIdx.y * 32768;
    int idx = blockIdx.x * 256 + threadIdx.x;   // 0..16383
    int t = idx & 7;
    int lane = (idx >> 3) & 63;
    int ks = (idx >> 9) & 3;
    int jt = idx >> 11;
    int j = jt * 16 + (lane & 15);
    int k = ks * 32 + (lane >> 4) * 8 + t;
    float w = W[j * D + k];
    __bf16 hi = (__bf16)w;
    o[idx] = hi;
    o[16384 + idx] = (__bf16)(w - (float)hi);
}

// ---------------- dual GEMM: y = h@Ws^T + b (fp32), z = h@Wn^T (bf16) ----
// z quarter-major with ZROWS rows/slab: z[((j>>5)*ZROWS + n)*32 + (j&31)].
__global__ __launch_bounds__(256) void dual_gemm(
        const float* __restrict__ h, const __bf16* __restrict__ Bs,
        const __bf16* __restrict__ Bn, const float* __restrict__ bias,
        float* __restrict__ y_self, __bf16* __restrict__ z) {
    const int wave = threadIdx.x >> 6;
    const int lane = threadIdx.x & 63;
    const int tile = blockIdx.x * 4 + wave;
    if (tile >= N_NODES / 16) return;
    const int n0 = tile * 16;
    const int row = n0 + (lane & 15);
    const int koff = (lane >> 4) * 8;

    U8 ahi[4], alo[4];
    #pragma unroll
    for (int ks = 0; ks < 4; ++ks) {
        const float* p = h + (size_t)row * D + ks * 32 + koff;
        float f[8];
        *(f32x4*)&f[0] = *(const f32x4*)p;
        *(f32x4*)&f[4] = *(const f32x4*)(p + 4);
        #pragma unroll
        for (int t = 0; t < 8; ++t) {
            __bf16 hi = (__bf16)f[t];
            ahi[ks].e[t] = hi;
            alo[ks].e[t] = (__bf16)(f[t] - (float)hi);
        }
    }

    const int jcol = lane & 15;
    const int r0 = (lane >> 4) * 4;

    #pragma unroll 2
    for (int jt = 0; jt < 8; ++jt) {
        f32x4 accS = {0.f, 0.f, 0.f, 0.f};
        f32x4 accN = {0.f, 0.f, 0.f, 0.f};
        #pragma unroll
        for (int ks = 0; ks < 4; ++ks) {
            const size_t off = (((size_t)jt * 4 + ks) * 64 + lane) * 8;
            bf16x8 wsh = *(const bf16x8*)(Bs + off);
            bf16x8 wsl = *(const bf16x8*)(Bs + 16384 + off);
            bf16x8 wnh = *(const bf16x8*)(Bn + off);
            bf16x8 wnl = *(const bf16x8*)(Bn + 16384 + off);
            accS = __builtin_amdgcn_mfma_f32_16x16x32_bf16(ahi[ks].v, wsh, accS, 0, 0, 0);
            accS = __builtin_amdgcn_mfma_f32_16x16x32_bf16(alo[ks].v, wsh, accS, 0, 0, 0);
            accS = __builtin_amdgcn_mfma_f32_16x16x32_bf16(ahi[ks].v, wsl, accS, 0, 0, 0);
            accN = __builtin_amdgcn_mfma_f32_16x16x32_bf16(ahi[ks].v, wnh, accN, 0, 0, 0);
            accN = __builtin_amdgcn_mfma_f32_16x16x32_bf16(alo[ks].v, wnh, accN, 0, 0, 0);
            accN = __builtin_amdgcn_mfma_f32_16x16x32_bf16(ahi[ks].v, wnl, accN, 0, 0, 0);
        }
        const int j = jt * 16 + jcol;
        const float bj = bias[j];
        const size_t zslab = (size_t)(j >> 5) * ZROWS;
        #pragma unroll
        for (int r = 0; r < 4; ++r) {
            const size_t n = n0 + r0 + r;
            y_self[n * D + j] = accS[r] + bj;
            z[(zslab + n) * 32 + (j & 31)] = (__bf16)accN[r];
        }
    }
}

// ---------------- aggregate z (slab, padded CSR) + add y_self ------------
// blockIdx%4 = q. Block = 16 nodes x quarter. Wave = 4 nodes;
// lane = (g:2)(sl:2)(cl:2). Slots own contiguous quarters of the padded
// range (len%16==0) -> i32x4 esrc loads, no tail loop, no divergent chains.
__global__ __launch_bounds__(256) void agg_add(
        const __bf16* __restrict__ zq, const int* __restrict__ esrc,
        const int* __restrict__ row_ptr, const float* __restrict__ inv_deg,
        const float* __restrict__ y_self, float* __restrict__ out, int do_relu) {
    const int q = blockIdx.x & 3;
    const int grp = blockIdx.x >> 2;
    const int wave = threadIdx.x >> 6;
    const int lane = threadIdx.x & 63;
    const int g  = lane >> 4;
    const int sl = (lane >> 2) & 3;
    const int cl = lane & 3;
    const int n = grp * 16 + wave * 4 + g;

    // independent prefetches (hide latency behind the gather)
    const float idg = inv_deg[n];
    const float* yp = y_self + (size_t)n * D + q * 32 + cl * 8;
    f32x4 y0 = *(const f32x4*)yp;
    f32x4 y1 = *(const f32x4*)(yp + 4);
    const int r0 = row_ptr[n];
    const int r1 = row_ptr[n + 1];
    const int len4 = (r1 - r0) >> 2;        // multiple of 4
    const int s0 = r0 + sl * len4;
    const __bf16* zbase = zq + (size_t)q * ZROWS * 32 + cl * 8;

    float acc[8] = {0.f, 0.f, 0.f, 0.f, 0.f, 0.f, 0.f, 0.f};
    for (int e = s0; e < s0 + len4; e += 4) {
        i32x4 idx = __builtin_nontemporal_load((const i32x4*)(esrc + e));
        U8 v0, v1, v2, v3;
        v0.v = *(const bf16x8*)(zbase + (size_t)idx.x * 32);
        v1.v = *(const bf16x8*)(zbase + (size_t)idx.y * 32);
        v2.v = *(const bf16x8*)(zbase + (size_t)idx.z * 32);
        v3.v = *(const bf16x8*)(zbase + (size_t)idx.w * 32);
        #pragma unroll
        for (int t = 0; t < 8; ++t)
            acc[t] += ((float)v0.e[t] + (float)v1.e[t]) + ((float)v2.e[t] + (float)v3.e[t]);
    }
    // fold 4 slots (bits 2-3 of lane)
    #pragma unroll
    for (int t = 0; t < 8; ++t) acc[t] += __shfl_down(acc[t], 8, 64);
    #pragma unroll
    for (int t = 0; t < 8; ++t) acc[t] += __shfl_down(acc[t], 4, 64);

    if (sl == 0) {
        float o[8];
        #pragma unroll
        for (int t = 0; t < 4; ++t) o[t] = y0[t] + acc[t] * idg;
        #pragma unroll
        for (int t = 0; t < 4; ++t) o[4 + t] = y1[t] + acc[4 + t] * idg;
        if (do_relu) {
            #pragma unroll
            for (int t = 0; t < 8; ++t) o[t] = fmaxf(o[t], 0.f);
        }
        float* op = out + (size_t)n * D + q * 32 + cl * 8;
        *(f32x4*)op = *(f32x4*)&o[0];
        *(f32x4*)(op + 4) = *(f32x4*)&o[4];
    }
}

extern "C" void kernel_launch(void* const* d_in, const int* in_sizes, int n_in,
                              void* d_out, int out_size, void* d_ws, size_t ws_size,
                              hipStream_t stream) {
    const float* x   = (const float*)d_in[0];
    const int* src   = (const int*)d_in[1];
    const int* dst   = (const int*)d_in[2];
    const float* Wn1 = (const float*)d_in[3];
    const float* Ws1 = (const float*)d_in[4];
    const float* b1  = (const float*)d_in[5];
    const float* Wn2 = (const float*)d_in[6];
    const float* Ws2 = (const float*)d_in[7];
    const float* b2  = (const float*)d_in[8];
    const float* Wn3 = (const float*)d_in[9];
    const float* Ws3 = (const float*)d_in[10];
    const float* b3  = (const float*)d_in[11];
    float* out = (float*)d_out;

    char* w = (char*)d_ws;
    float* inv_deg  = (float*)w;                w += 50176 * 4;
    int* counts     = (int*)w;                  w += 50176 * 4;
    int* counts_sh  = (int*)w;                  w += 8 * NSH * 4;
    int* row_ptr    = (int*)w;                  w += 50432 * 4;
    int* blocksums  = (int*)w;                  w += 64 * 4;
    int* blockoffs  = (int*)w;                  w += 64 * 4;
    int* esrc       = (int*)w;                  w += (size_t)ESRC_CAP * 4;
    __bf16* Bpk     = (__bf16*)w;               w += 6 * 32768 * 2;
    __bf16* zbuf    = (__bf16*)w;               w += (size_t)4 * ZROWS * 32 * 2;
    float* bufA     = (float*)w;                // N*D floats

    int* pos_local = (int*)zbuf;   // dead before zero_zrow / dual_gemm touch zbuf

    const __bf16* PWs1 = Bpk + 0 * 32768, *PWn1 = Bpk + 1 * 32768;
    const __bf16* PWs2 = Bpk + 2 * 32768, *PWn2 = Bpk + 3 * 32768;
    const __bf16* PWs3 = Bpk + 4 * 32768, *PWn3 = Bpk + 5 * 32768;

    // ---- CSR build with shadow histograms + sentinel padding ----
    zero_sh<<<(8 * NSH / 4 + 255) / 256, 256, 0, stream>>>((i32x4*)counts_sh, 8 * NSH / 4);
    fill_esrc<<<(ESRC_CAP / 4 + 255) / 256, 256, 0, stream>>>((i32x4*)esrc, ESRC_CAP / 4);
    hist8<<<N_EDGES / 512, 512, 0, stream>>>(dst, counts_sh, pos_local, N_EDGES);
    shadow_scan<<<(N_NODES + 255) / 256, 256, 0, stream>>>(counts_sh, counts, inv_deg);
    scan_p1<<<NCHUNK, SCAN_BLK, 0, stream>>>(counts, row_ptr, blocksums);
    scan_p2<<<1, 64, 0, stream>>>(blocksums, blockoffs);
    scan_p3<<<NCHUNK, SCAN_BLK, 0, stream>>>(row_ptr, blockoffs, blocksums);
    scatter8<<<N_EDGES / 512, 512, 0, stream>>>(src, dst, pos_local, counts_sh,
                                                row_ptr, esrc, N_EDGES);
    zero_zrow<<<1, 128, 0, stream>>>(zbuf);     // after scatter (pos_local aliased)
    pack_w<<<dim3(64, 6), 256, 0, stream>>>(Ws1, Wn1, Ws2, Wn2, Ws3, Wn3, Bpk);

    const int ggrid = (N_NODES / 16 + 3) / 4;     // 782
    const int agrid = (N_NODES / 16) * 4;         // 12500

    // layer 1: h=x -> bufA (relu)
    dual_gemm<<<ggrid, 256, 0, stream>>>(x, PWs1, PWn1, b1, bufA, zbuf);
    agg_add<<<agrid, 256, 0, stream>>>(zbuf, esrc, row_ptr, inv_deg, bufA, bufA, 1);

    // layer 2: h=bufA -> d_out (relu)
    dual_gemm<<<ggrid, 256, 0, stream>>>(bufA, PWs2, PWn2, b2, out, zbuf);
    agg_add<<<agrid, 256, 0, stream>>>(zbuf, esrc, row_ptr, inv_deg, out, out, 1);

    // layer 3: h=d_out -> d_out (no relu), y_self staged in bufA
    dual_gemm<<<ggrid, 256, 0, stream>>>(out, PWs3, PWn3, b3, bufA, zbuf);
    agg_add<<<agrid, 256, 0, stream>>>(zbuf, esrc, row_ptr, inv_deg, bufA, out, 0);
}

// Round 10
// 455.252 us; speedup vs baseline: 1.2166x; 1.0442x over previous
//
#include <hip/hip_runtime.h>

// GraphSAGE 3-layer, N=50000, E=1.6M, D=128.
// R10: dual_gemm amortizes weight fragments over 4 tiles/wave (64 nodes);
//      merged init kernel; scan_p2 folded into scan_p3. agg_add = R9.

constexpr int N_NODES = 50000;
constexpr int N_EDGES = 1600000;
constexpr int D = 128;
constexpr int SCAN_BLK = 1024;
constexpr int NCHUNK = (N_NODES + SCAN_BLK - 1) / SCAN_BLK;  // 49
constexpr int NSH = 50048;            // shadow stride (ints)
constexpr int ESRC_CAP = 2100000;     // padded-edge capacity (mult of 4)
constexpr int SENT = 50000;           // sentinel node id (zero z-row)
constexpr int ZROWS = 50001;          // slab rows incl sentinel
constexpr int NTILE = 3125;           // 16-row MFMA tiles

typedef __bf16 bf16x8 __attribute__((ext_vector_type(8)));
typedef float f32x4 __attribute__((ext_vector_type(4)));
typedef int i32x4 __attribute__((ext_vector_type(4)));
union U8 { bf16x8 v; __bf16 e[8]; };

// ---------------- init: zero shadows, sentinel-fill esrc, zero z rows ----
__global__ void init_ws(i32x4* __restrict__ csh4, i32x4* __restrict__ esrc4,
                        __bf16* __restrict__ z) {
    int i = blockIdx.x * 256 + threadIdx.x;
    if (i < 8 * NSH / 4) csh4[i] = (i32x4){0, 0, 0, 0};
    if (i < ESRC_CAP / 4) esrc4[i] = (i32x4){SENT, SENT, SENT, SENT};
    if (i < 128) {
        int q = i >> 5, c = i & 31;
        z[((size_t)q * ZROWS + SENT) * 32 + c] = (__bf16)0.f;
    }
}

// ---------------- 8-shadow histogram + per-edge local pos ----------------
__global__ __launch_bounds__(512) void hist8(const int* __restrict__ dst,
                                             int* __restrict__ counts_sh,
                                             int* __restrict__ pos_local, int n) {
    int e = blockIdx.x * 512 + threadIdx.x;
    if (e < n) {
        int s = blockIdx.x & 7;
        pos_local[e] = atomicAdd(&counts_sh[s * NSH + dst[e]], 1);
    }
}

// ---------------- per-node shadow prefix + deg + padded count ------------
__global__ void shadow_scan(int* __restrict__ counts_sh, int* __restrict__ counts,
                            float* __restrict__ inv_deg) {
    int d = blockIdx.x * 256 + threadIdx.x;
    if (d >= N_NODES) return;
    int run = 0;
    #pragma unroll
    for (int s = 0; s < 8; ++s) {
        int c = counts_sh[s * NSH + d];
        counts_sh[s * NSH + d] = run;   // exclusive prefix in place
        run += c;
    }
    counts[d] = (run + 15) & ~15;       // padded count (mult of 16)
    inv_deg[d] = 1.0f / fmaxf((float)run, 1.0f);
}

// ---------------- scan phase 1 (padded counts -> local scan) -------------
__global__ __launch_bounds__(SCAN_BLK) void scan_p1(const int* __restrict__ counts,
                                                    int* __restrict__ row_ptr,
                                                    int* __restrict__ blocksums) {
    __shared__ int wsum[16];
    __shared__ int wpre[16];
    const int t = threadIdx.x;
    const int i = blockIdx.x * SCAN_BLK + t;
    const int lane = t & 63, w = t >> 6;
    int v = (i < N_NODES) ? counts[i] : 0;
    int x = v;
    #pragma unroll
    for (int off = 1; off < 64; off <<= 1) {
        int tt = __shfl_up(x, off, 64);
        if (lane >= off) x += tt;
    }
    if (lane == 63) wsum[w] = x;
    __syncthreads();
    if (t < 16) {
        int s = wsum[t];
        int y = s;
        #pragma unroll
        for (int off = 1; off < 16; off <<= 1) {
            int tt = __shfl_up(y, off, 64);
            if (t >= off) y += tt;
        }
        wpre[t] = y - s;
    }
    __syncthreads();
    if (i < N_NODES) row_ptr[i] = wpre[w] + (x - v);
    if (t == SCAN_BLK - 1) blocksums[blockIdx.x] = wpre[15] + wsum[15];
}

// ---------------- scan phase 2+3: per-block offset + add -----------------
__global__ __launch_bounds__(SCAN_BLK) void scan_p3(int* __restrict__ row_ptr,
                                                    const int* __restrict__ blocksums) {
    __shared__ int soff;
    const int t = threadIdx.x;
    if (t < 64) {
        int v = (t < NCHUNK && t < blockIdx.x) ? blocksums[t] : 0;
        #pragma unroll
        for (int off = 32; off >= 1; off >>= 1) v += __shfl_down(v, off, 64);
        if (t == 0) soff = v;
    }
    __syncthreads();
    const int i = blockIdx.x * SCAN_BLK + t;
    if (i < N_NODES) row_ptr[i] += soff;
    if (blockIdx.x == NCHUNK - 1 && t == 0)
        row_ptr[N_NODES] = soff + blocksums[NCHUNK - 1];
}

// ---------------- scatter edges (atomic-free) ----------------------------
__global__ __launch_bounds__(512) void scatter8(const int* __restrict__ src,
                                                const int* __restrict__ dst,
                                                const int* __restrict__ pos_local,
                                                const int* __restrict__ counts_sh,
                                                const int* __restrict__ row_ptr,
                                                int* __restrict__ esrc, int n) {
    int e = blockIdx.x * 512 + threadIdx.x;
    if (e < n) {
        int d = dst[e];
        int s = blockIdx.x & 7;
        esrc[row_ptr[d] + counts_sh[s * NSH + d] + pos_local[e]] = src[e];
    }
}

// ---------------- pack W into MFMA B-fragment order, hi+lo ---------------
__global__ void pack_w(const float* __restrict__ w0, const float* __restrict__ w1,
                       const float* __restrict__ w2, const float* __restrict__ w3,
                       const float* __restrict__ w4, const float* __restrict__ w5,
                       __bf16* __restrict__ outbase) {
    const float* ws[6] = {w0, w1, w2, w3, w4, w5};
    const float* W = ws[blockIdx.y];
    __bf16* o = outbase + (size_t)blockIdx.y * 32768;
    int idx = blockIdx.x * 256 + threadIdx.x;   // 0..16383
    int t = idx & 7;
    int lane = (idx >> 3) & 63;
    int ks = (idx >> 9) & 3;
    int jt = idx >> 11;
    int j = jt * 16 + (lane & 15);
    int k = ks * 32 + (lane >> 4) * 8 + t;
    float w = W[j * D + k];
    __bf16 hi = (__bf16)w;
    o[idx] = hi;
    o[16384 + idx] = (__bf16)(w - (float)hi);
}

// ---------------- dual GEMM: y = h@Ws^T + b (fp32), z = h@Wn^T (bf16) ----
// 4 tiles (64 rows) per wave: A-frags in registers, each weight fragment
// feeds 4 MFMAs (weight traffic amortized 4x vs 1 tile/wave).
// z quarter-major with ZROWS rows/slab: z[((j>>5)*ZROWS + n)*32 + (j&31)].
__global__ __launch_bounds__(256, 1) void dual_gemm(
        const float* __restrict__ h, const __bf16* __restrict__ Bs,
        const __bf16* __restrict__ Bn, const float* __restrict__ bias,
        float* __restrict__ y_self, __bf16* __restrict__ z) {
    const int wave = threadIdx.x >> 6;
    const int lane = threadIdx.x & 63;
    const int grp = blockIdx.x * 4 + wave;     // group of 4 tiles
    const int t0 = grp * 4;
    if (t0 >= NTILE) return;
    const int jcol = lane & 15;
    const int quad = lane >> 4;
    const int koff = quad * 8;

    U8 ahi[4][4], alo[4][4];
    #pragma unroll
    for (int t = 0; t < 4; ++t) {
        const int tile = min(t0 + t, NTILE - 1);
        const int row = tile * 16 + jcol;
        #pragma unroll
        for (int ks = 0; ks < 4; ++ks) {
            const float* p = h + (size_t)row * D + ks * 32 + koff;
            float f[8];
            *(f32x4*)&f[0] = *(const f32x4*)p;
            *(f32x4*)&f[4] = *(const f32x4*)(p + 4);
            #pragma unroll
            for (int u = 0; u < 8; ++u) {
                __bf16 hi = (__bf16)f[u];
                ahi[t][ks].e[u] = hi;
                alo[t][ks].e[u] = (__bf16)(f[u] - (float)hi);
            }
        }
    }

    const int r0 = quad * 4;

    for (int jt = 0; jt < 8; ++jt) {
        f32x4 accS[4], accN[4];
        #pragma unroll
        for (int t = 0; t < 4; ++t) {
            accS[t] = (f32x4){0.f, 0.f, 0.f, 0.f};
            accN[t] = (f32x4){0.f, 0.f, 0.f, 0.f};
        }
        #pragma unroll
        for (int ks = 0; ks < 4; ++ks) {
            const size_t off = (((size_t)jt * 4 + ks) * 64 + lane) * 8;
            bf16x8 wsh = *(const bf16x8*)(Bs + off);
            bf16x8 wsl = *(const bf16x8*)(Bs + 16384 + off);
            bf16x8 wnh = *(const bf16x8*)(Bn + off);
            bf16x8 wnl = *(const bf16x8*)(Bn + 16384 + off);
            #pragma unroll
            for (int t = 0; t < 4; ++t) {
                accS[t] = __builtin_amdgcn_mfma_f32_16x16x32_bf16(ahi[t][ks].v, wsh, accS[t], 0, 0, 0);
                accS[t] = __builtin_amdgcn_mfma_f32_16x16x32_bf16(alo[t][ks].v, wsh, accS[t], 0, 0, 0);
                accS[t] = __builtin_amdgcn_mfma_f32_16x16x32_bf16(ahi[t][ks].v, wsl, accS[t], 0, 0, 0);
                accN[t] = __builtin_amdgcn_mfma_f32_16x16x32_bf16(ahi[t][ks].v, wnh, accN[t], 0, 0, 0);
                accN[t] = __builtin_amdgcn_mfma_f32_16x16x32_bf16(alo[t][ks].v, wnh, accN[t], 0, 0, 0);
                accN[t] = __builtin_amdgcn_mfma_f32_16x16x32_bf16(ahi[t][ks].v, wnl, accN[t], 0, 0, 0);
            }
        }
        const int j = jt * 16 + jcol;
        const float bj = bias[j];
        const size_t zslab = (size_t)(j >> 5) * ZROWS;
        #pragma unroll
        for (int t = 0; t < 4; ++t) {
            const int tile = t0 + t;
            if (tile >= NTILE) break;
            const int n0 = tile * 16;
            #pragma unroll
            for (int r = 0; r < 4; ++r) {
                const size_t n = n0 + r0 + r;
                y_self[n * D + j] = accS[t][r] + bj;
                z[(zslab + n) * 32 + (j & 31)] = (__bf16)accN[t][r];
            }
        }
    }
}

// ---------------- aggregate z (slab, padded CSR) + add y_self ------------
// blockIdx%4 = q. Block = 16 nodes x quarter. Wave = 4 nodes;
// lane = (g:2)(sl:2)(cl:2). Slots own contiguous quarters of the padded
// range (len%16==0) -> i32x4 esrc loads, no tail loop, no divergent chains.
__global__ __launch_bounds__(256) void agg_add(
        const __bf16* __restrict__ zq, const int* __restrict__ esrc,
        const int* __restrict__ row_ptr, const float* __restrict__ inv_deg,
        const float* __restrict__ y_self, float* __restrict__ out, int do_relu) {
    const int q = blockIdx.x & 3;
    const int grp = blockIdx.x >> 2;
    const int wave = threadIdx.x >> 6;
    const int lane = threadIdx.x & 63;
    const int g  = lane >> 4;
    const int sl = (lane >> 2) & 3;
    const int cl = lane & 3;
    const int n = grp * 16 + wave * 4 + g;

    // independent prefetches (hide latency behind the gather)
    const float idg = inv_deg[n];
    const float* yp = y_self + (size_t)n * D + q * 32 + cl * 8;
    f32x4 y0 = *(const f32x4*)yp;
    f32x4 y1 = *(const f32x4*)(yp + 4);
    const int r0 = row_ptr[n];
    const int r1 = row_ptr[n + 1];
    const int len4 = (r1 - r0) >> 2;        // multiple of 4
    const int s0 = r0 + sl * len4;
    const __bf16* zbase = zq + (size_t)q * ZROWS * 32 + cl * 8;

    float acc[8] = {0.f, 0.f, 0.f, 0.f, 0.f, 0.f, 0.f, 0.f};
    for (int e = s0; e < s0 + len4; e += 4) {
        i32x4 idx = __builtin_nontemporal_load((const i32x4*)(esrc + e));
        U8 v0, v1, v2, v3;
        v0.v = *(const bf16x8*)(zbase + (size_t)idx.x * 32);
        v1.v = *(const bf16x8*)(zbase + (size_t)idx.y * 32);
        v2.v = *(const bf16x8*)(zbase + (size_t)idx.z * 32);
        v3.v = *(const bf16x8*)(zbase + (size_t)idx.w * 32);
        #pragma unroll
        for (int t = 0; t < 8; ++t)
            acc[t] += ((float)v0.e[t] + (float)v1.e[t]) + ((float)v2.e[t] + (float)v3.e[t]);
    }
    // fold 4 slots (bits 2-3 of lane)
    #pragma unroll
    for (int t = 0; t < 8; ++t) acc[t] += __shfl_down(acc[t], 8, 64);
    #pragma unroll
    for (int t = 0; t < 8; ++t) acc[t] += __shfl_down(acc[t], 4, 64);

    if (sl == 0) {
        float o[8];
        #pragma unroll
        for (int t = 0; t < 4; ++t) o[t] = y0[t] + acc[t] * idg;
        #pragma unroll
        for (int t = 0; t < 4; ++t) o[4 + t] = y1[t] + acc[4 + t] * idg;
        if (do_relu) {
            #pragma unroll
            for (int t = 0; t < 8; ++t) o[t] = fmaxf(o[t], 0.f);
        }
        float* op = out + (size_t)n * D + q * 32 + cl * 8;
        *(f32x4*)op = *(f32x4*)&o[0];
        *(f32x4*)(op + 4) = *(f32x4*)&o[4];
    }
}

extern "C" void kernel_launch(void* const* d_in, const int* in_sizes, int n_in,
                              void* d_out, int out_size, void* d_ws, size_t ws_size,
                              hipStream_t stream) {
    const float* x   = (const float*)d_in[0];
    const int* src   = (const int*)d_in[1];
    const int* dst   = (const int*)d_in[2];
    const float* Wn1 = (const float*)d_in[3];
    const float* Ws1 = (const float*)d_in[4];
    const float* b1  = (const float*)d_in[5];
    const float* Wn2 = (const float*)d_in[6];
    const float* Ws2 = (const float*)d_in[7];
    const float* b2  = (const float*)d_in[8];
    const float* Wn3 = (const float*)d_in[9];
    const float* Ws3 = (const float*)d_in[10];
    const float* b3  = (const float*)d_in[11];
    float* out = (float*)d_out;

    char* w = (char*)d_ws;
    float* inv_deg  = (float*)w;                w += 50176 * 4;
    int* counts     = (int*)w;                  w += 50176 * 4;
    int* counts_sh  = (int*)w;                  w += 8 * NSH * 4;
    int* row_ptr    = (int*)w;                  w += 50432 * 4;
    int* blocksums  = (int*)w;                  w += 64 * 4;
    int* esrc       = (int*)w;                  w += (size_t)ESRC_CAP * 4;
    __bf16* Bpk     = (__bf16*)w;               w += 6 * 32768 * 2;
    __bf16* zbuf    = (__bf16*)w;               w += (size_t)4 * ZROWS * 32 * 2;
    float* bufA     = (float*)w;                // N*D floats

    int* pos_local = (int*)bufA;   // dead once dual_gemm layer-1 writes y_self

    const __bf16* PWs1 = Bpk + 0 * 32768, *PWn1 = Bpk + 1 * 32768;
    const __bf16* PWs2 = Bpk + 2 * 32768, *PWn2 = Bpk + 3 * 32768;
    const __bf16* PWs3 = Bpk + 4 * 32768, *PWn3 = Bpk + 5 * 32768;

    // ---- CSR build with shadow histograms + sentinel padding ----
    init_ws<<<(ESRC_CAP / 4 + 255) / 256, 256, 0, stream>>>(
        (i32x4*)counts_sh, (i32x4*)esrc, zbuf);
    hist8<<<N_EDGES / 512, 512, 0, stream>>>(dst, counts_sh, pos_local, N_EDGES);
    shadow_scan<<<(N_NODES + 255) / 256, 256, 0, stream>>>(counts_sh, counts, inv_deg);
    scan_p1<<<NCHUNK, SCAN_BLK, 0, stream>>>(counts, row_ptr, blocksums);
    scan_p3<<<NCHUNK, SCAN_BLK, 0, stream>>>(row_ptr, blocksums);
    scatter8<<<N_EDGES / 512, 512, 0, stream>>>(src, dst, pos_local, counts_sh,
                                                row_ptr, esrc, N_EDGES);
    pack_w<<<dim3(64, 6), 256, 0, stream>>>(Ws1, Wn1, Ws2, Wn2, Ws3, Wn3, Bpk);

    const int ngrp = (NTILE + 3) / 4;             // 782 groups of 4 tiles
    const int ggrid = (ngrp + 3) / 4;             // 196 blocks x 4 waves
    const int agrid = (N_NODES / 16) * 4;         // 12500

    // layer 1: h=x -> bufA (relu)
    dual_gemm<<<ggrid, 256, 0, stream>>>(x, PWs1, PWn1, b1, bufA, zbuf);
    agg_add<<<agrid, 256, 0, stream>>>(zbuf, esrc, row_ptr, inv_deg, bufA, bufA, 1);

    // layer 2: h=bufA -> d_out (relu)
    dual_gemm<<<ggrid, 256, 0, stream>>>(bufA, PWs2, PWn2, b2, out, zbuf);
    agg_add<<<agrid, 256, 0, stream>>>(zbuf, esrc, row_ptr, inv_deg, out, out, 1);

    // layer 3: h=d_out -> d_out (no relu), y_self staged in bufA
    dual_gemm<<<ggrid, 256, 0, stream>>>(out, PWs3, PWn3, b3, bufA, zbuf);
    agg_add<<<agrid, 256, 0, stream>>>(zbuf, esrc, row_ptr, inv_deg, bufA, out, 0);
}